// Round 21
// baseline (259.060 us; speedup 1.0000x reference)
//
#include <hip/hip_runtime.h>
#include <hip/hip_bf16.h>
#include <math.h>

#define NA 100000
#define NP 150000
#define EMB 64
#define NE 3200000
#define BATCH 65536
#define EPS 1e-8f
#define F8 128.0f
#define INVF8 (1.0f / 128.0f)

// bucketed counting-sort parameters (fixed-capacity padded regions)
#define SH_A 8                                   // author bucket = 256 nodes
#define SH_P 9                                   // paper bucket = 512 nodes
#define NB_A ((NA + (1 << SH_A) - 1) >> SH_A)    // 391
#define NB_P ((NP + (1 << SH_P) - 1) >> SH_P)    // 293
#define NBT (NB_A + NB_P)                        // 684
#define CAP_A 9216                               // mean 8192, ~11 sigma margin
#define CAP_P 12288                              // mean 10922, ~13 sigma margin
#define TOT_A (NB_A * CAP_A)
#define TOT_P (NB_P * CAP_P)
#define PACK_SH 18
#define PACK_MASK ((1u << PACK_SH) - 1)
#define CHUNK 4096
#define EPT 8                                    // edges per thread (CHUNK/512)
#define NOENT 0xFFFFFFFFu

typedef float f32x2 __attribute__((ext_vector_type(2)));

#if defined(__has_builtin)
#if __has_builtin(__builtin_amdgcn_cvt_pk_f32_fp8) && __has_builtin(__builtin_amdgcn_cvt_pk_fp8_f32)
#define HW_FP8 1
#endif
#endif

// pack 4 floats -> 4 fp8 (one u32)
__device__ inline unsigned pk_fp8x4(float a, float b, float c, float d) {
#ifdef HW_FP8
    int t = __builtin_amdgcn_cvt_pk_fp8_f32(a, b, 0, false);
    t = __builtin_amdgcn_cvt_pk_fp8_f32(c, d, t, true);
    return (unsigned)t;
#else
    auto enc = [](float x) -> unsigned {
        union { float f; unsigned u; } t; t.f = x;
        unsigned s = t.u >> 31; int e = (int)((t.u >> 23) & 0xFF) - 127;
        unsigned m = (t.u >> 20) & 7;
        int E = e + 7;
        if (E <= 0) return s << 7;
        if (E > 15) { E = 15; m = 7; }
        return (s << 7) | ((unsigned)E << 3) | m;
    };
    return enc(a) | (enc(b) << 8) | (enc(c) << 16) | (enc(d) << 24);
#endif
}

// unpack word-half (2 fp8) -> 2 floats
__device__ inline f32x2 up_fp8x2(unsigned v, bool hi) {
#ifdef HW_FP8
    return hi ? __builtin_amdgcn_cvt_pk_f32_fp8((int)v, true)
              : __builtin_amdgcn_cvt_pk_f32_fp8((int)v, false);
#else
    auto dec = [](unsigned b) -> float {
        unsigned s = b >> 7, e = (b >> 3) & 0xF, m = b & 7;
        if (e == 0) return (s ? -1.0f : 1.0f) * (float)m * 0.001953125f;
        union { unsigned u; float f; } t;
        t.u = (s << 31) | ((e + 120) << 23) | (m << 20);
        return t.f;
    };
    unsigned sh = hi ? 16 : 0;
    f32x2 r;
    r.x = dec((v >> sh) & 0xFF);
    r.y = dec((v >> (sh + 8)) & 0xFF);
    return r;
#endif
}

__device__ inline unsigned pack_bf16(float a, float b) {
    __hip_bfloat16 ha = __float2bfloat16(a);
    __hip_bfloat16 hb = __float2bfloat16(b);
    unsigned ua = *(unsigned short*)&ha;
    unsigned ub = *(unsigned short*)&hb;
    return ua | (ub << 16);
}

__device__ inline float bf_lo(unsigned u) { return __uint_as_float(u << 16); }
__device__ inline float bf_hi(unsigned u) { return __uint_as_float(u & 0xffff0000u); }

// ------- init: bucket cursors + zero-sentinel rows for all fp8 arrays ---------

__global__ void init_cur(int* __restrict__ bcur, uint2* __restrict__ sa0,
                         uint2* __restrict__ sp0, uint2* __restrict__ sa1,
                         uint2* __restrict__ sp1) {
    int i = blockIdx.x * blockDim.x + threadIdx.x;
    if (i < NB_A) bcur[i] = i * CAP_A;
    else if (i < NBT) bcur[i] = (i - NB_A) * CAP_P;
    if (i < 8)       sa0[(size_t)NA * 8 + i]        = uint2{0, 0};
    else if (i < 16) sp0[(size_t)NP * 8 + (i - 8)]  = uint2{0, 0};
    else if (i < 24) sa1[(size_t)NA * 8 + (i - 16)] = uint2{0, 0};
    else if (i < 32) sp1[(size_t)NP * 8 + (i - 24)] = uint2{0, 0};
}

// ------- stage: reg-cached edges, LDS bin, DIRECT-ADDRESSED flat write-out ----

__global__ void __launch_bounds__(512) stage_kernel(
        const int* __restrict__ ea, const int* __restrict__ ep,
        int* __restrict__ bcur,
        unsigned* __restrict__ stg_a, unsigned* __restrict__ stg_p) {
    __shared__ unsigned lsbuf[2 * CHUNK];   // 32 KB bucket-sorted entries
    __shared__ int gposl[2 * CHUNK];        // 32 KB final global positions
    __shared__ int hh[NBT];                 // histogram, then scatter cursor
    __shared__ int lbase[NBT + 1];          // local run base (+sentinel)
    __shared__ int gbase[NBT];              // global run base
    __shared__ int tsum[512];
    int t = threadIdx.x;

    // phase 0: load this thread's edges into registers
    int e0 = blockIdx.x * CHUNK;
    int e1 = min(e0 + CHUNK, NE);
    int av[EPT], pv[EPT];
    #pragma unroll
    for (int k = 0; k < EPT; ++k) {
        int e = e0 + t + k * 512;
        bool ok = (e < e1);
        av[k] = ok ? ea[e] : -1;
        pv[k] = ok ? ep[e] : -1;
    }

    // phase 1: histogram from regs
    for (int i = t; i < NBT; i += 512) hh[i] = 0;
    __syncthreads();
    #pragma unroll
    for (int k = 0; k < EPT; ++k) {
        if (av[k] >= 0) {
            atomicAdd(&hh[av[k] >> SH_A], 1);
            atomicAdd(&hh[NB_A + (pv[k] >> SH_P)], 1);
        }
    }
    __syncthreads();

    // phase 2: exclusive scan over NBT (each thread owns 2 slots)
    int v0 = (2 * t < NBT) ? hh[2 * t] : 0;
    int v1 = (2 * t + 1 < NBT) ? hh[2 * t + 1] : 0;
    tsum[t] = v0 + v1;
    __syncthreads();
    for (int o = 1; o < 512; o <<= 1) {
        int v = (t >= o) ? tsum[t - o] : 0;
        __syncthreads();
        tsum[t] += v;
        __syncthreads();
    }
    int excl = (t == 0) ? 0 : tsum[t - 1];
    if (2 * t < NBT) lbase[2 * t] = excl;
    if (2 * t + 1 < NBT) lbase[2 * t + 1] = excl + v0;
    if (t == 511) lbase[NBT] = tsum[511];   // sentinel = total entries
    __syncthreads();

    // phase 3: reserve global ranges (one atomic per non-empty bucket)
    for (int i = t; i < NBT; i += 512) {
        int c = hh[i];
        gbase[i] = c ? atomicAdd(&bcur[i], c) : 0;
    }
    __syncthreads();
    for (int i = t; i < NBT; i += 512) hh[i] = lbase[i];   // become cursors
    __syncthreads();

    // phase 4: scatter into LDS from regs, recording final global position
    #pragma unroll
    for (int k = 0; k < EPT; ++k) {
        if (av[k] >= 0) {
            int ba = av[k] >> SH_A;
            int bp = NB_A + (pv[k] >> SH_P);
            int sa = atomicAdd(&hh[ba], 1);
            lsbuf[sa] = ((unsigned)(av[k] & ((1 << SH_A) - 1)) << PACK_SH) | (unsigned)pv[k];
            gposl[sa] = gbase[ba] + (sa - lbase[ba]);          // author: >= 0
            int sp = atomicAdd(&hh[bp], 1);
            lsbuf[sp] = ((unsigned)(pv[k] & ((1 << SH_P) - 1)) << PACK_SH) | (unsigned)av[k];
            gposl[sp] = ~(gbase[bp] + (sp - lbase[bp]));       // paper: < 0
        }
    }
    __syncthreads();

    // phase 5: flat linear write-out (coalesced runs, no search)
    int total = lbase[NBT];
    for (int i = t; i < total; i += 512) {
        unsigned v = lsbuf[i];
        int p = gposl[i];
        if (p >= 0) stg_a[p] = v;
        else        stg_p[~p] = v;
    }
}

// ------- per-bucket CSR build, 512 threads, register-cached entries -----------

template <int S, int CAP, int NNODES, int KMAX>
__device__ __forceinline__ void build_side(
    const unsigned* __restrict__ stg, const int* __restrict__ bend, int b,
    int* __restrict__ off, float* __restrict__ rs, int* __restrict__ dg,
    int* __restrict__ csr, const float4* __restrict__ emb, uint2* __restrict__ sfp8,
    int* cnt /*S ints; doubles as cur*/, int* tsum /*512*/, int* ls /*CAP ints*/) {
    int t = threadIdx.x;                 // 0..511
    int node0 = b * S;
    int nloc = min(S, NNODES - node0);
    int p0 = b * CAP, p1 = bend[b];
    int nent = p1 - p0;

    // phase 0: load this thread's entries (strided) into registers
    unsigned ent[KMAX];
    #pragma unroll
    for (int k = 0; k < KMAX; ++k) {
        int i = t + k * 512;
        ent[k] = (i < nent) ? stg[p0 + i] : NOENT;
    }

    // phase 1: node histogram (LDS atomics from regs)
    for (int i = t; i < S; i += 512) cnt[i] = 0;
    __syncthreads();
    #pragma unroll
    for (int k = 0; k < KMAX; ++k)
        if (ent[k] != NOENT) atomicAdd(&cnt[ent[k] >> PACK_SH], 1);
    __syncthreads();

    // phase 2: scan (thread t owns slot t, t < S <= 512)
    int val = (t < S) ? cnt[t] : 0;
    tsum[t] = val;
    __syncthreads();
    for (int o = 1; o < 512; o <<= 1) {
        int v = (t >= o) ? tsum[t - o] : 0;
        __syncthreads();
        tsum[t] += v;
        __syncthreads();
    }
    int excl = (t == 0) ? 0 : tsum[t - 1];
    if (t < S) {
        if (t < nloc) {
            off[node0 + t] = p0 + excl;
            dg[node0 + t] = val;
            rs[node0 + t] = rsqrtf((float)val + EPS);
        }
        cnt[t] = excl;           // cur, bucket-local
    }
    __syncthreads();

    // phase 3: scatter into LDS from regs (random LDS = cheap)
    #pragma unroll
    for (int k = 0; k < KMAX; ++k)
        if (ent[k] != NOENT) {
            int slot = atomicAdd(&cnt[ent[k] >> PACK_SH], 1);
            ls[slot] = (int)((ent[k] & PACK_MASK) << 6);
        }
    __syncthreads();

    // phase 4: sequential coalesced copy LDS -> csr (int4; padding garbage ok)
    int rounded = (nent + 3) & ~3;
    for (int i = t * 4; i < rounded; i += 2048) {
        int4 w = {ls[i], ls[i + 1], ls[i + 2], ls[i + 3]};
        *(int4*)(csr + p0 + i) = w;
    }

    // phase 5: fused scale0: fp8-encode this block's node rows (8 thr/node)
    int q = t & 7;
    for (int ln = t >> 3; ln < nloc; ln += 64) {
        int n = node0 + ln;
        float r = rs[n] * F8;
        float4 v0 = emb[n * 16 + q * 2];
        float4 v1 = emb[n * 16 + q * 2 + 1];
        uint2 o;
        o.x = pk_fp8x4(r * v0.x, r * v0.y, r * v0.z, r * v0.w);
        o.y = pk_fp8x4(r * v1.x, r * v1.y, r * v1.z, r * v1.w);
        sfp8[(size_t)n * 8 + q] = o;
    }
}

__global__ void __launch_bounds__(512) build_all(
                          const unsigned* __restrict__ stg_a,
                          const unsigned* __restrict__ stg_p,
                          const int* __restrict__ bcur,
                          int* __restrict__ off_a, float* __restrict__ rs_a,
                          int* __restrict__ dg_a, int* __restrict__ csr_a,
                          int* __restrict__ off_p, float* __restrict__ rs_p,
                          int* __restrict__ dg_p, int* __restrict__ csr_p,
                          const float4* __restrict__ a_emb, const float4* __restrict__ p_emb,
                          uint2* __restrict__ sa0, uint2* __restrict__ sp0) {
    __shared__ int ls[CAP_P];      // 48 KB
    __shared__ int cnt[512];       // histogram, then cursors
    __shared__ int tsum[512];
    int b = blockIdx.x;
    if (b < NB_A)
        build_side<256, CAP_A, NA, (CAP_A + 511) / 512>(
            stg_a, bcur, b, off_a, rs_a, dg_a, csr_a, a_emb, sa0, cnt, tsum, ls);
    else
        build_side<512, CAP_P, NP, (CAP_P + 511) / 512>(
            stg_p, bcur + NB_A, b - NB_A, off_p, rs_p, dg_p, csr_p, p_emb, sp0, cnt, tsum, ls);
}

// ------- pull conv: 8-lane group per node, DOUBLE-BUFFERED row loads ----------
// Two iterations of row loads in flight per group (16 outstanding gathers).
// A/B unrolled buffers avoid register rotation. Speculative csr reads stay
// inside padded bucket regions; out-of-range edges -> zero-sentinel row.
template <int LAYER, bool IS_PAPER>
__global__ void pullg(const int* __restrict__ off_s, const int* __restrict__ dg_s,
                      const int* __restrict__ csr_s, const float* __restrict__ rs_s,
                      const uint2* __restrict__ src,     // opposite side's fp8 rows
                      const float4* __restrict__ emb,
                      uint4* __restrict__ io,
                      uint2* __restrict__ sout) {
    constexpr int NW = (IS_PAPER ? NP : NA) / 8;
    int wid = (int)(((size_t)blockIdx.x * blockDim.x + threadIdx.x) >> 6);
    if (wid >= NW) return;
    int lane = threadIdx.x & 63;
    int g = lane >> 3;
    int q = lane & 7;
    int n = wid * 8 + g;

    const char* srcb = (const char*)src;
    unsigned zoff = (unsigned)(IS_PAPER ? NA : NP) << 6;

    int start = off_s[n];
    int deg = dg_s[n];
    float rsd = rs_s[n];
    unsigned q8 = (unsigned)(q << 3);

    f32x2 acc[4];
    acc[0] = f32x2{0, 0}; acc[1] = f32x2{0, 0};
    acc[2] = f32x2{0, 0}; acc[3] = f32x2{0, 0};

    // prologue: buffer A = edges [0,8)
    unsigned idA = (q < deg) ? (unsigned)csr_s[start + q] : zoff;
    uint2 vA[8], vB[8];
    #pragma unroll
    for (int k = 0; k < 8; ++k) {
        unsigned ide = (unsigned)__shfl((int)idA, k, 8);
        vA[k] = *(const uint2*)(srcb + (ide | q8));
    }

    int t = 0;
    while (t < deg) {
        // issue B = edges [t+8, t+16) before consuming A
        {
            unsigned idv = (unsigned)csr_s[start + t + 8 + q];
            unsigned idB = (t + 8 + q < deg) ? idv : zoff;
            #pragma unroll
            for (int k = 0; k < 8; ++k) {
                unsigned ide = (unsigned)__shfl((int)idB, k, 8);
                vB[k] = *(const uint2*)(srcb + (ide | q8));
            }
        }
        #pragma unroll
        for (int k = 0; k < 8; ++k) {
            acc[0] += up_fp8x2(vA[k].x, false);
            acc[1] += up_fp8x2(vA[k].x, true);
            acc[2] += up_fp8x2(vA[k].y, false);
            acc[3] += up_fp8x2(vA[k].y, true);
        }
        t += 8;
        if (t >= deg) break;
        // issue A = edges [t+8, t+16) before consuming B
        {
            unsigned idv = (unsigned)csr_s[start + t + 8 + q];
            unsigned idA2 = (t + 8 + q < deg) ? idv : zoff;
            #pragma unroll
            for (int k = 0; k < 8; ++k) {
                unsigned ide = (unsigned)__shfl((int)idA2, k, 8);
                vA[k] = *(const uint2*)(srcb + (ide | q8));
            }
        }
        #pragma unroll
        for (int k = 0; k < 8; ++k) {
            acc[0] += up_fp8x2(vB[k].x, false);
            acc[1] += up_fp8x2(vB[k].x, true);
            acc[2] += up_fp8x2(vB[k].y, false);
            acc[3] += up_fp8x2(vB[k].y, true);
        }
        t += 8;
    }

    // epilogue: every lane writes its 8-dim slice of its node
    float inv = rsd * INVF8;
    if (LAYER == 1) {
        int f4 = n * 16 + q * 2;
        float4 e0 = emb[f4];
        float4 e1 = emb[f4 + 1];
        float d = (float)deg;
        float sw = 1.0f - d / (d + EPS);
        float l1[8];
        l1[0] = sw * e0.x + inv * acc[0].x;
        l1[1] = sw * e0.y + inv * acc[0].y;
        l1[2] = sw * e0.z + inv * acc[1].x;
        l1[3] = sw * e0.w + inv * acc[1].y;
        l1[4] = sw * e1.x + inv * acc[2].x;
        l1[5] = sw * e1.y + inv * acc[2].y;
        l1[6] = sw * e1.z + inv * acc[3].x;
        l1[7] = sw * e1.w + inv * acc[3].y;
        float gs = F8 * rsd;                   // fp8 scaled copy for layer 2
        uint2 sv;
        sv.x = pk_fp8x4(gs * l1[0], gs * l1[1], gs * l1[2], gs * l1[3]);
        sv.y = pk_fp8x4(gs * l1[4], gs * l1[5], gs * l1[6], gs * l1[7]);
        sout[(size_t)n * 8 + q] = sv;
        float c = 1.0f + sw;                   // io = bf16(emb + (1+sw)*l1)
        uint4 ov;
        ov.x = pack_bf16(e0.x + c * l1[0], e0.y + c * l1[1]);
        ov.y = pack_bf16(e0.z + c * l1[2], e0.w + c * l1[3]);
        ov.z = pack_bf16(e1.x + c * l1[4], e1.y + c * l1[5]);
        ov.w = pack_bf16(e1.z + c * l1[6], e1.w + c * l1[7]);
        io[(size_t)n * 8 + q] = ov;
    } else {
        uint4 pr = io[(size_t)n * 8 + q];
        uint4 ov;
        ov.x = pack_bf16(bf_lo(pr.x) + inv * acc[0].x, bf_hi(pr.x) + inv * acc[0].y);
        ov.y = pack_bf16(bf_lo(pr.y) + inv * acc[1].x, bf_hi(pr.y) + inv * acc[1].y);
        ov.z = pack_bf16(bf_lo(pr.z) + inv * acc[2].x, bf_hi(pr.z) + inv * acc[2].y);
        ov.w = pack_bf16(bf_lo(pr.w) + inv * acc[3].x, bf_hi(pr.w) + inv * acc[3].y);
        io[(size_t)n * 8 + q] = ov;
    }
}

// ---------------- batch gather + predict (bf16 finals) ----------------

__global__ void gather_kernel(const unsigned short* __restrict__ fa,
                              const unsigned short* __restrict__ fp,
                              const int* __restrict__ authors, const int* __restrict__ papers,
                              float* __restrict__ out, int batch) {
    int t = blockIdx.x * blockDim.x + threadIdx.x;
    int b = t >> 6;
    int d = t & 63;
    if (b >= batch) return;
    float la = __uint_as_float((unsigned)fa[authors[b] * EMB + d] << 16);
    float lp = __uint_as_float((unsigned)fp[papers[b] * EMB + d] << 16);
    out[batch + b * EMB + d] = la;                 // latest_author
    out[batch + batch * EMB + b * EMB + d] = lp;   // latest_paper
    float prod = la * lp;
    #pragma unroll
    for (int off = 32; off > 0; off >>= 1)
        prod += __shfl_down(prod, off, 64);
    if (d == 0)
        out[b] = 1.0f / (1.0f + expf(-prod));      // predict
}

// ---------------- launch ----------------

extern "C" void kernel_launch(void* const* d_in, const int* in_sizes, int n_in,
                              void* d_out, int out_size, void* d_ws, size_t ws_size,
                              hipStream_t stream) {
    const float* author_emb = (const float*)d_in[0];
    const float* paper_emb  = (const float*)d_in[1];
    const int*   authors    = (const int*)d_in[2];
    const int*   papers     = (const int*)d_in[3];
    const int*   edge_a     = (const int*)d_in[4];
    const int*   edge_p     = (const int*)d_in[5];
    float* out = (float*)d_out;

    char* ws = (char*)d_ws;
    size_t woff = 0;
    auto alloc = [&](size_t bytes) {
        void* p = ws + woff;
        woff += (bytes + 255) & ~(size_t)255;
        return p;
    };
    int*   bcur    = (int*)alloc(NBT * sizeof(int));
    int*   off_a   = (int*)alloc(NA * sizeof(int));
    int*   off_p   = (int*)alloc(NP * sizeof(int));
    int*   dg_a    = (int*)alloc(NA * sizeof(int));
    int*   dg_p    = (int*)alloc(NP * sizeof(int));
    float* rs_a    = (float*)alloc(NA * sizeof(float));
    float* rs_p    = (float*)alloc(NP * sizeof(float));
    int*   csr_a   = (int*)alloc((size_t)TOT_A * sizeof(int));
    int*   csr_p   = (int*)alloc((size_t)TOT_P * sizeof(int));
    uint2* sa0     = (uint2*)alloc((size_t)(NA + 1) * EMB);   // fp8 scaled inputs + zero row
    uint2* sp0     = (uint2*)alloc((size_t)(NP + 1) * EMB);
    uint2* sa1     = (uint2*)alloc((size_t)(NA + 1) * EMB);   // fp8 scaled layer-1 out + zero row
    uint2* sp1     = (uint2*)alloc((size_t)(NP + 1) * EMB);
    uint4* a1      = (uint4*)alloc((size_t)NA * EMB * 2);     // bf16 pre2 then final author
    uint4* p1      = (uint4*)alloc((size_t)NP * EMB * 2);     // bf16 pre2 then final paper
    // DEDICATED staging (r13 lesson: no aliasing with live buffers)
    unsigned* stg_a = (unsigned*)alloc((size_t)TOT_A * sizeof(unsigned));
    unsigned* stg_p = (unsigned*)alloc((size_t)TOT_P * sizeof(unsigned));
    (void)ws_size;   // total ~124 MB; ~142 MB proven available (rounds 0-1)

    // CSR build: fixed-capacity bucket regions (no histogram pass)
    init_cur<<<(NBT + 255) / 256, 256, 0, stream>>>(bcur, sa0, sp0, sa1, sp1);
    stage_kernel<<<(NE + CHUNK - 1) / CHUNK, 512, 0, stream>>>(edge_a, edge_p, bcur, stg_a, stg_p);
    build_all<<<NBT, 512, 0, stream>>>(stg_a, stg_p, bcur,
                                       off_a, rs_a, dg_a, csr_a,
                                       off_p, rs_p, dg_p, csr_p,
                                       (const float4*)author_emb, (const float4*)paper_emb,
                                       sa0, sp0);

    const unsigned GP = (unsigned)(((long long)(NP / 8) * 64 + 255) / 256);  // paper-dst blocks
    const unsigned GA = (unsigned)(((long long)(NA / 8) * 64 + 255) / 256);  // author-dst blocks

    // layer 1 (side-split: one source array live per dispatch)
    pullg<1, true><<<GP, 256, 0, stream>>>(
        off_p, dg_p, csr_p, rs_p, sa0, (const float4*)paper_emb, p1, sp1);
    pullg<1, false><<<GA, 256, 0, stream>>>(
        off_a, dg_a, csr_a, rs_a, sp0, (const float4*)author_emb, a1, sa1);

    // layer 2 (sources sa1/sp1 written by layer 1)
    pullg<2, true><<<GP, 256, 0, stream>>>(
        off_p, dg_p, csr_p, rs_p, sa1, (const float4*)paper_emb, p1, nullptr);
    pullg<2, false><<<GA, 256, 0, stream>>>(
        off_a, dg_a, csr_a, rs_a, sp1, (const float4*)author_emb, a1, nullptr);

    // batch gather + predict
    {
        long long total = (long long)BATCH * 64;
        gather_kernel<<<(unsigned)((total + 255) / 256), 256, 0, stream>>>(
            (const unsigned short*)a1, (const unsigned short*)p1, authors, papers, out, BATCH);
    }
}

// Round 22
// 247.046 us; speedup vs baseline: 1.0486x; 1.0486x over previous
//
#include <hip/hip_runtime.h>
#include <hip/hip_bf16.h>
#include <math.h>

#define NA 100000
#define NP 150000
#define EMB 64
#define NE 3200000
#define BATCH 65536
#define EPS 1e-8f
#define F8 128.0f
#define INVF8 (1.0f / 128.0f)

// bucketed counting-sort parameters (fixed-capacity padded regions)
#define SH_A 8                                   // author bucket = 256 nodes
#define SH_P 9                                   // paper bucket = 512 nodes
#define NB_A ((NA + (1 << SH_A) - 1) >> SH_A)    // 391
#define NB_P ((NP + (1 << SH_P) - 1) >> SH_P)    // 293
#define NBT (NB_A + NB_P)                        // 684
#define CAP_A 9216                               // mean 8192, ~11 sigma margin
#define CAP_P 12288                              // mean 10922, ~13 sigma margin
#define TOT_A (NB_A * CAP_A)
#define TOT_P (NB_P * CAP_P)
#define PACK_SH 18
#define PACK_MASK ((1u << PACK_SH) - 1)
#define CHUNK 4096
#define EPT 8                                    // edges per thread (CHUNK/512)
#define NOENT 0xFFFFFFFFu

typedef float f32x2 __attribute__((ext_vector_type(2)));

#if defined(__has_builtin)
#if __has_builtin(__builtin_amdgcn_cvt_pk_f32_fp8) && __has_builtin(__builtin_amdgcn_cvt_pk_fp8_f32)
#define HW_FP8 1
#endif
#endif

// pack 4 floats -> 4 fp8 (one u32)
__device__ inline unsigned pk_fp8x4(float a, float b, float c, float d) {
#ifdef HW_FP8
    int t = __builtin_amdgcn_cvt_pk_fp8_f32(a, b, 0, false);
    t = __builtin_amdgcn_cvt_pk_fp8_f32(c, d, t, true);
    return (unsigned)t;
#else
    auto enc = [](float x) -> unsigned {
        union { float f; unsigned u; } t; t.f = x;
        unsigned s = t.u >> 31; int e = (int)((t.u >> 23) & 0xFF) - 127;
        unsigned m = (t.u >> 20) & 7;
        int E = e + 7;
        if (E <= 0) return s << 7;
        if (E > 15) { E = 15; m = 7; }
        return (s << 7) | ((unsigned)E << 3) | m;
    };
    return enc(a) | (enc(b) << 8) | (enc(c) << 16) | (enc(d) << 24);
#endif
}

// unpack word-half (2 fp8) -> 2 floats
__device__ inline f32x2 up_fp8x2(unsigned v, bool hi) {
#ifdef HW_FP8
    return hi ? __builtin_amdgcn_cvt_pk_f32_fp8((int)v, true)
              : __builtin_amdgcn_cvt_pk_f32_fp8((int)v, false);
#else
    auto dec = [](unsigned b) -> float {
        unsigned s = b >> 7, e = (b >> 3) & 0xF, m = b & 7;
        if (e == 0) return (s ? -1.0f : 1.0f) * (float)m * 0.001953125f;
        union { unsigned u; float f; } t;
        t.u = (s << 31) | ((e + 120) << 23) | (m << 20);
        return t.f;
    };
    unsigned sh = hi ? 16 : 0;
    f32x2 r;
    r.x = dec((v >> sh) & 0xFF);
    r.y = dec((v >> (sh + 8)) & 0xFF);
    return r;
#endif
}

__device__ inline unsigned pack_bf16(float a, float b) {
    __hip_bfloat16 ha = __float2bfloat16(a);
    __hip_bfloat16 hb = __float2bfloat16(b);
    unsigned ua = *(unsigned short*)&ha;
    unsigned ub = *(unsigned short*)&hb;
    return ua | (ub << 16);
}

__device__ inline float bf_lo(unsigned u) { return __uint_as_float(u << 16); }
__device__ inline float bf_hi(unsigned u) { return __uint_as_float(u & 0xffff0000u); }

// ------- init: bucket cursors + zero-sentinel rows for all fp8 arrays ---------

__global__ void init_cur(int* __restrict__ bcur, uint2* __restrict__ sa0,
                         uint2* __restrict__ sp0, uint2* __restrict__ sa1,
                         uint2* __restrict__ sp1) {
    int i = blockIdx.x * blockDim.x + threadIdx.x;
    if (i < NB_A) bcur[i] = i * CAP_A;
    else if (i < NBT) bcur[i] = (i - NB_A) * CAP_P;
    if (i < 8)       sa0[(size_t)NA * 8 + i]        = uint2{0, 0};
    else if (i < 16) sp0[(size_t)NP * 8 + (i - 8)]  = uint2{0, 0};
    else if (i < 24) sa1[(size_t)NA * 8 + (i - 16)] = uint2{0, 0};
    else if (i < 32) sp1[(size_t)NP * 8 + (i - 24)] = uint2{0, 0};
}

// ------- stage: reg-cached edges, LDS bin, DIRECT-ADDRESSED flat write-out ----

__global__ void __launch_bounds__(512) stage_kernel(
        const int* __restrict__ ea, const int* __restrict__ ep,
        int* __restrict__ bcur,
        unsigned* __restrict__ stg_a, unsigned* __restrict__ stg_p) {
    __shared__ unsigned lsbuf[2 * CHUNK];   // 32 KB bucket-sorted entries
    __shared__ int gposl[2 * CHUNK];        // 32 KB final global positions
    __shared__ int hh[NBT];                 // histogram, then scatter cursor
    __shared__ int lbase[NBT + 1];          // local run base (+sentinel)
    __shared__ int gbase[NBT];              // global run base
    __shared__ int tsum[512];
    int t = threadIdx.x;

    // phase 0: load this thread's edges into registers
    int e0 = blockIdx.x * CHUNK;
    int e1 = min(e0 + CHUNK, NE);
    int av[EPT], pv[EPT];
    #pragma unroll
    for (int k = 0; k < EPT; ++k) {
        int e = e0 + t + k * 512;
        bool ok = (e < e1);
        av[k] = ok ? ea[e] : -1;
        pv[k] = ok ? ep[e] : -1;
    }

    // phase 1: histogram from regs
    for (int i = t; i < NBT; i += 512) hh[i] = 0;
    __syncthreads();
    #pragma unroll
    for (int k = 0; k < EPT; ++k) {
        if (av[k] >= 0) {
            atomicAdd(&hh[av[k] >> SH_A], 1);
            atomicAdd(&hh[NB_A + (pv[k] >> SH_P)], 1);
        }
    }
    __syncthreads();

    // phase 2: exclusive scan over NBT (each thread owns 2 slots)
    int v0 = (2 * t < NBT) ? hh[2 * t] : 0;
    int v1 = (2 * t + 1 < NBT) ? hh[2 * t + 1] : 0;
    tsum[t] = v0 + v1;
    __syncthreads();
    for (int o = 1; o < 512; o <<= 1) {
        int v = (t >= o) ? tsum[t - o] : 0;
        __syncthreads();
        tsum[t] += v;
        __syncthreads();
    }
    int excl = (t == 0) ? 0 : tsum[t - 1];
    if (2 * t < NBT) lbase[2 * t] = excl;
    if (2 * t + 1 < NBT) lbase[2 * t + 1] = excl + v0;
    if (t == 511) lbase[NBT] = tsum[511];   // sentinel = total entries
    __syncthreads();

    // phase 3: reserve global ranges (one atomic per non-empty bucket)
    for (int i = t; i < NBT; i += 512) {
        int c = hh[i];
        gbase[i] = c ? atomicAdd(&bcur[i], c) : 0;
    }
    __syncthreads();
    for (int i = t; i < NBT; i += 512) hh[i] = lbase[i];   // become cursors
    __syncthreads();

    // phase 4: scatter into LDS from regs, recording final global position
    #pragma unroll
    for (int k = 0; k < EPT; ++k) {
        if (av[k] >= 0) {
            int ba = av[k] >> SH_A;
            int bp = NB_A + (pv[k] >> SH_P);
            int sa = atomicAdd(&hh[ba], 1);
            lsbuf[sa] = ((unsigned)(av[k] & ((1 << SH_A) - 1)) << PACK_SH) | (unsigned)pv[k];
            gposl[sa] = gbase[ba] + (sa - lbase[ba]);          // author: >= 0
            int sp = atomicAdd(&hh[bp], 1);
            lsbuf[sp] = ((unsigned)(pv[k] & ((1 << SH_P) - 1)) << PACK_SH) | (unsigned)av[k];
            gposl[sp] = ~(gbase[bp] + (sp - lbase[bp]));       // paper: < 0
        }
    }
    __syncthreads();

    // phase 5: flat linear write-out (coalesced runs, no search)
    int total = lbase[NBT];
    for (int i = t; i < total; i += 512) {
        unsigned v = lsbuf[i];
        int p = gposl[i];
        if (p >= 0) stg_a[p] = v;
        else        stg_p[~p] = v;
    }
}

// ------- per-bucket CSR build, 512 threads, register-cached entries -----------

template <int S, int CAP, int NNODES, int KMAX>
__device__ __forceinline__ void build_side(
    const unsigned* __restrict__ stg, const int* __restrict__ bend, int b,
    int* __restrict__ off, float* __restrict__ rs, int* __restrict__ dg,
    int* __restrict__ csr, const float4* __restrict__ emb, uint2* __restrict__ sfp8,
    int* cnt /*S ints; doubles as cur*/, int* tsum /*512*/, int* ls /*CAP ints*/) {
    int t = threadIdx.x;                 // 0..511
    int node0 = b * S;
    int nloc = min(S, NNODES - node0);
    int p0 = b * CAP, p1 = bend[b];
    int nent = p1 - p0;

    // phase 0: load this thread's entries (strided) into registers
    unsigned ent[KMAX];
    #pragma unroll
    for (int k = 0; k < KMAX; ++k) {
        int i = t + k * 512;
        ent[k] = (i < nent) ? stg[p0 + i] : NOENT;
    }

    // phase 1: node histogram (LDS atomics from regs)
    for (int i = t; i < S; i += 512) cnt[i] = 0;
    __syncthreads();
    #pragma unroll
    for (int k = 0; k < KMAX; ++k)
        if (ent[k] != NOENT) atomicAdd(&cnt[ent[k] >> PACK_SH], 1);
    __syncthreads();

    // phase 2: scan (thread t owns slot t, t < S <= 512)
    int val = (t < S) ? cnt[t] : 0;
    tsum[t] = val;
    __syncthreads();
    for (int o = 1; o < 512; o <<= 1) {
        int v = (t >= o) ? tsum[t - o] : 0;
        __syncthreads();
        tsum[t] += v;
        __syncthreads();
    }
    int excl = (t == 0) ? 0 : tsum[t - 1];
    if (t < S) {
        if (t < nloc) {
            off[node0 + t] = p0 + excl;
            dg[node0 + t] = val;
            rs[node0 + t] = rsqrtf((float)val + EPS);
        }
        cnt[t] = excl;           // cur, bucket-local
    }
    __syncthreads();

    // phase 3: scatter into LDS from regs (random LDS = cheap)
    #pragma unroll
    for (int k = 0; k < KMAX; ++k)
        if (ent[k] != NOENT) {
            int slot = atomicAdd(&cnt[ent[k] >> PACK_SH], 1);
            ls[slot] = (int)((ent[k] & PACK_MASK) << 6);
        }
    __syncthreads();

    // phase 4: sequential coalesced copy LDS -> csr (int4; padding garbage ok)
    int rounded = (nent + 3) & ~3;
    for (int i = t * 4; i < rounded; i += 2048) {
        int4 w = {ls[i], ls[i + 1], ls[i + 2], ls[i + 3]};
        *(int4*)(csr + p0 + i) = w;
    }

    // phase 5: fused scale0: fp8-encode this block's node rows (8 thr/node)
    int q = t & 7;
    for (int ln = t >> 3; ln < nloc; ln += 64) {
        int n = node0 + ln;
        float r = rs[n] * F8;
        float4 v0 = emb[n * 16 + q * 2];
        float4 v1 = emb[n * 16 + q * 2 + 1];
        uint2 o;
        o.x = pk_fp8x4(r * v0.x, r * v0.y, r * v0.z, r * v0.w);
        o.y = pk_fp8x4(r * v1.x, r * v1.y, r * v1.z, r * v1.w);
        sfp8[(size_t)n * 8 + q] = o;
    }
}

__global__ void __launch_bounds__(512) build_all(
                          const unsigned* __restrict__ stg_a,
                          const unsigned* __restrict__ stg_p,
                          const int* __restrict__ bcur,
                          int* __restrict__ off_a, float* __restrict__ rs_a,
                          int* __restrict__ dg_a, int* __restrict__ csr_a,
                          int* __restrict__ off_p, float* __restrict__ rs_p,
                          int* __restrict__ dg_p, int* __restrict__ csr_p,
                          const float4* __restrict__ a_emb, const float4* __restrict__ p_emb,
                          uint2* __restrict__ sa0, uint2* __restrict__ sp0) {
    __shared__ int ls[CAP_P];      // 48 KB
    __shared__ int cnt[512];       // histogram, then cursors
    __shared__ int tsum[512];
    int b = blockIdx.x;
    if (b < NB_A)
        build_side<256, CAP_A, NA, (CAP_A + 511) / 512>(
            stg_a, bcur, b, off_a, rs_a, dg_a, csr_a, a_emb, sa0, cnt, tsum, ls);
    else
        build_side<512, CAP_P, NP, (CAP_P + 511) / 512>(
            stg_p, bcur + NB_A, b - NB_A, off_p, rs_p, dg_p, csr_p, p_emb, sp0, cnt, tsum, ls);
}

// ------- pull conv: FUSED both sides, 8-lane group per node, id-prefetched ----
// Both destination sides in one dispatch (tail overlap: author waves fill CUs
// while paper waves drain). wave = 8 nodes; lane q accumulates dims [8q,8q+8)
// of its node directly (no cross-lane reduce). r20 inner loop (28 VGPR).
template <int LAYER>
__global__ void pullg(const int* __restrict__ off_a, const int* __restrict__ off_p,
                      const int* __restrict__ dg_a, const int* __restrict__ dg_p,
                      const int* __restrict__ csr_a, const int* __restrict__ csr_p,
                      const float* __restrict__ rs_a, const float* __restrict__ rs_p,
                      const uint2* __restrict__ src_from_a,
                      const uint2* __restrict__ src_from_p,
                      const float4* __restrict__ a_emb, const float4* __restrict__ p_emb,
                      uint4* __restrict__ a_io, uint4* __restrict__ p_io,
                      uint2* __restrict__ sa_out, uint2* __restrict__ sp_out) {
    constexpr int NPW = NP / 8;   // 18750 paper waves
    constexpr int NAW = NA / 8;   // 12500 author waves
    int wid = (int)(((size_t)blockIdx.x * blockDim.x + threadIdx.x) >> 6);
    int lane = threadIdx.x & 63;
    int g = lane >> 3;
    int q = lane & 7;

    int n;
    bool is_paper;
    if (wid < NPW) { is_paper = true; n = wid * 8 + g; }
    else if (wid < NPW + NAW) { is_paper = false; n = (wid - NPW) * 8 + g; }
    else return;

    const int *off, *dg, *csr;
    const char* srcb;
    const float4* emb;
    uint4* io;
    uint2* sout;
    const float* rs;
    unsigned zoff;
    if (is_paper) {
        off = off_p; dg = dg_p; csr = csr_p; srcb = (const char*)src_from_a;
        emb = p_emb; io = p_io; sout = sp_out; rs = rs_p;
        zoff = (unsigned)NA << 6;
    } else {
        off = off_a; dg = dg_a; csr = csr_a; srcb = (const char*)src_from_p;
        emb = a_emb; io = a_io; sout = sa_out; rs = rs_a;
        zoff = (unsigned)NP << 6;
    }

    int start = off[n];
    int deg = dg[n];
    float rsd = rs[n];
    unsigned q8 = (unsigned)(q << 3);

    f32x2 acc[4];
    acc[0] = f32x2{0, 0}; acc[1] = f32x2{0, 0};
    acc[2] = f32x2{0, 0}; acc[3] = f32x2{0, 0};

    // id prefetch pipeline (padded bucket regions make speculative reads safe)
    unsigned myid_next = (q < deg) ? (unsigned)csr[start + q] : zoff;
    for (int t = 0; t < deg; t += 8) {
        unsigned myid = myid_next;
        {
            unsigned idv = (unsigned)csr[start + t + 8 + q];
            myid_next = (t + 8 + q < deg) ? idv : zoff;
        }
        uint2 v[8];
        #pragma unroll
        for (int k = 0; k < 8; ++k) {
            unsigned ide = (unsigned)__shfl((int)myid, k, 8);
            v[k] = *(const uint2*)(srcb + (ide | q8));
        }
        #pragma unroll
        for (int k = 0; k < 8; ++k) {
            acc[0] += up_fp8x2(v[k].x, false);
            acc[1] += up_fp8x2(v[k].x, true);
            acc[2] += up_fp8x2(v[k].y, false);
            acc[3] += up_fp8x2(v[k].y, true);
        }
    }

    // epilogue: every lane writes its 8-dim slice of its node
    float inv = rsd * INVF8;
    if (LAYER == 1) {
        int f4 = n * 16 + q * 2;
        float4 e0 = emb[f4];
        float4 e1 = emb[f4 + 1];
        float d = (float)deg;
        float sw = 1.0f - d / (d + EPS);
        float l1[8];
        l1[0] = sw * e0.x + inv * acc[0].x;
        l1[1] = sw * e0.y + inv * acc[0].y;
        l1[2] = sw * e0.z + inv * acc[1].x;
        l1[3] = sw * e0.w + inv * acc[1].y;
        l1[4] = sw * e1.x + inv * acc[2].x;
        l1[5] = sw * e1.y + inv * acc[2].y;
        l1[6] = sw * e1.z + inv * acc[3].x;
        l1[7] = sw * e1.w + inv * acc[3].y;
        float gs = F8 * rsd;                   // fp8 scaled copy for layer 2
        uint2 sv;
        sv.x = pk_fp8x4(gs * l1[0], gs * l1[1], gs * l1[2], gs * l1[3]);
        sv.y = pk_fp8x4(gs * l1[4], gs * l1[5], gs * l1[6], gs * l1[7]);
        sout[(size_t)n * 8 + q] = sv;
        float c = 1.0f + sw;                   // io = bf16(emb + (1+sw)*l1)
        uint4 ov;
        ov.x = pack_bf16(e0.x + c * l1[0], e0.y + c * l1[1]);
        ov.y = pack_bf16(e0.z + c * l1[2], e0.w + c * l1[3]);
        ov.z = pack_bf16(e1.x + c * l1[4], e1.y + c * l1[5]);
        ov.w = pack_bf16(e1.z + c * l1[6], e1.w + c * l1[7]);
        io[(size_t)n * 8 + q] = ov;
    } else {
        uint4 pr = io[(size_t)n * 8 + q];
        uint4 ov;
        ov.x = pack_bf16(bf_lo(pr.x) + inv * acc[0].x, bf_hi(pr.x) + inv * acc[0].y);
        ov.y = pack_bf16(bf_lo(pr.y) + inv * acc[1].x, bf_hi(pr.y) + inv * acc[1].y);
        ov.z = pack_bf16(bf_lo(pr.z) + inv * acc[2].x, bf_hi(pr.z) + inv * acc[2].y);
        ov.w = pack_bf16(bf_lo(pr.w) + inv * acc[3].x, bf_hi(pr.w) + inv * acc[3].y);
        io[(size_t)n * 8 + q] = ov;
    }
}

// ---------------- batch gather + predict (bf16 finals) ----------------

__global__ void gather_kernel(const unsigned short* __restrict__ fa,
                              const unsigned short* __restrict__ fp,
                              const int* __restrict__ authors, const int* __restrict__ papers,
                              float* __restrict__ out, int batch) {
    int t = blockIdx.x * blockDim.x + threadIdx.x;
    int b = t >> 6;
    int d = t & 63;
    if (b >= batch) return;
    float la = __uint_as_float((unsigned)fa[authors[b] * EMB + d] << 16);
    float lp = __uint_as_float((unsigned)fp[papers[b] * EMB + d] << 16);
    out[batch + b * EMB + d] = la;                 // latest_author
    out[batch + batch * EMB + b * EMB + d] = lp;   // latest_paper
    float prod = la * lp;
    #pragma unroll
    for (int off = 32; off > 0; off >>= 1)
        prod += __shfl_down(prod, off, 64);
    if (d == 0)
        out[b] = 1.0f / (1.0f + expf(-prod));      // predict
}

// ---------------- launch ----------------

extern "C" void kernel_launch(void* const* d_in, const int* in_sizes, int n_in,
                              void* d_out, int out_size, void* d_ws, size_t ws_size,
                              hipStream_t stream) {
    const float* author_emb = (const float*)d_in[0];
    const float* paper_emb  = (const float*)d_in[1];
    const int*   authors    = (const int*)d_in[2];
    const int*   papers     = (const int*)d_in[3];
    const int*   edge_a     = (const int*)d_in[4];
    const int*   edge_p     = (const int*)d_in[5];
    float* out = (float*)d_out;

    char* ws = (char*)d_ws;
    size_t woff = 0;
    auto alloc = [&](size_t bytes) {
        void* p = ws + woff;
        woff += (bytes + 255) & ~(size_t)255;
        return p;
    };
    int*   bcur    = (int*)alloc(NBT * sizeof(int));
    int*   off_a   = (int*)alloc(NA * sizeof(int));
    int*   off_p   = (int*)alloc(NP * sizeof(int));
    int*   dg_a    = (int*)alloc(NA * sizeof(int));
    int*   dg_p    = (int*)alloc(NP * sizeof(int));
    float* rs_a    = (float*)alloc(NA * sizeof(float));
    float* rs_p    = (float*)alloc(NP * sizeof(float));
    int*   csr_a   = (int*)alloc((size_t)TOT_A * sizeof(int));
    int*   csr_p   = (int*)alloc((size_t)TOT_P * sizeof(int));
    uint2* sa0     = (uint2*)alloc((size_t)(NA + 1) * EMB);   // fp8 scaled inputs + zero row
    uint2* sp0     = (uint2*)alloc((size_t)(NP + 1) * EMB);
    uint2* sa1     = (uint2*)alloc((size_t)(NA + 1) * EMB);   // fp8 scaled layer-1 out + zero row
    uint2* sp1     = (uint2*)alloc((size_t)(NP + 1) * EMB);
    uint4* a1      = (uint4*)alloc((size_t)NA * EMB * 2);     // bf16 pre2 then final author
    uint4* p1      = (uint4*)alloc((size_t)NP * EMB * 2);     // bf16 pre2 then final paper
    // DEDICATED staging (r13 lesson: no aliasing with live buffers)
    unsigned* stg_a = (unsigned*)alloc((size_t)TOT_A * sizeof(unsigned));
    unsigned* stg_p = (unsigned*)alloc((size_t)TOT_P * sizeof(unsigned));
    (void)ws_size;   // total ~124 MB; ~142 MB proven available (rounds 0-1)

    // CSR build: fixed-capacity bucket regions (no histogram pass)
    init_cur<<<(NBT + 255) / 256, 256, 0, stream>>>(bcur, sa0, sp0, sa1, sp1);
    stage_kernel<<<(NE + CHUNK - 1) / CHUNK, 512, 0, stream>>>(edge_a, edge_p, bcur, stg_a, stg_p);
    build_all<<<NBT, 512, 0, stream>>>(stg_a, stg_p, bcur,
                                       off_a, rs_a, dg_a, csr_a,
                                       off_p, rs_p, dg_p, csr_p,
                                       (const float4*)author_emb, (const float4*)paper_emb,
                                       sa0, sp0);

    const long long PULL_WAVES = (long long)(NP / 8 + NA / 8);   // 31250
    const unsigned PULL_GRID = (unsigned)((PULL_WAVES * 64 + 255) / 256);

    // layer 1: fused both-sides pull (bf16 pre2 + fp8 sa1/sp1)
    pullg<1><<<PULL_GRID, 256, 0, stream>>>(
        off_a, off_p, dg_a, dg_p, csr_a, csr_p, rs_a, rs_p,
        sa0, sp0,
        (const float4*)author_emb, (const float4*)paper_emb,
        a1, p1, sa1, sp1);

    // layer 2: fused both-sides pull, io += (rsd/F8)*acc in place
    pullg<2><<<PULL_GRID, 256, 0, stream>>>(
        off_a, off_p, dg_a, dg_p, csr_a, csr_p, rs_a, rs_p,
        sa1, sp1,
        (const float4*)author_emb, (const float4*)paper_emb,
        a1, p1, nullptr, nullptr);

    // batch gather + predict
    {
        long long total = (long long)BATCH * 64;
        gather_kernel<<<(unsigned)((total + 255) / 256), 256, 0, stream>>>(
            (const unsigned short*)a1, (const unsigned short*)p1, authors, papers, out, BATCH);
    }
}